// Round 11
// baseline (105.681 us; speedup 1.0000x reference)
//
#include <hip/hip_runtime.h>
#include <hip/hip_bf16.h>

// NT-Xent (SimCLR) fused loss, MI355X gfx950. Round 11: ATOMIC-FREE tiles.
// Identical to R10 (persistent zero-LDS register GEMM, fp8 MX MFMA, register
// row sums, shallow col shuffles) except every atomicAdd into the hot S[]
// is replaced by a plain store into a unique (slot,row) cell of a partial
// slab Spart[72][8192]:
//   slot g (0..7):            row-sum partials of block (g, rb)
//   slot 8+(jj-1)*2+wm:       col-sum partials of tile jj (wm disambiguates
//                             the two waves covering the same columns)
// Finalize sums the 72 slots per row. Theory: device-scope atomic completion
// (memory-side, cross-XCD, vmcnt-counted) is the invariant ~21K-cyc/tile
// stall across R7-R10; plain stores are fire-and-forget.
//
// ws layout: [pos: N floats][Spart: 72*N floats][zn8: N*D fp8 bytes]

#define N_TOT 8192
#define BATCH 4096
#define DIM   256                    // fp8 bytes per row
#define NT_TILES 64                  // 8192 / 128
#define NSLOT 72

typedef int   v8i32 __attribute__((ext_vector_type(8)));
typedef float f32x4 __attribute__((ext_vector_type(4)));

// One wave per row: 64 lanes x float4 -> 4 fp8 bytes/lane.
// Also zeroes Spart (one float4 per thread) and out[0].
__global__ __launch_bounds__(256) void normalize_kernel(
    const float* __restrict__ z, unsigned char* __restrict__ zn8,
    float* __restrict__ Spart, float* __restrict__ out) {
  const int wave = threadIdx.x >> 6;
  const int lane = threadIdx.x & 63;
  const int row  = blockIdx.x * 4 + wave;
  float4 v = ((const float4*)(z + (size_t)row * DIM))[lane];
  float ss = v.x * v.x + v.y * v.y + v.z * v.z + v.w * v.w;
#pragma unroll
  for (int m = 1; m <= 32; m <<= 1) ss += __shfl_xor(ss, m);
  float inv = 1.0f / sqrtf(ss);
  int p01 = __builtin_amdgcn_cvt_pk_fp8_f32(v.x * inv, v.y * inv, 0, false);
  int p23 = __builtin_amdgcn_cvt_pk_fp8_f32(v.z * inv, v.w * inv, 0, false);
  unsigned int packed =
      ((unsigned int)p01 & 0xffffu) | ((unsigned int)p23 << 16);
  ((unsigned int*)(zn8 + (size_t)row * DIM))[lane] = packed;

  const int gt = blockIdx.x * 256 + threadIdx.x;
  if (gt < (NSLOT * N_TOT) / 4) ((float4*)Spart)[gt] = (float4){0, 0, 0, 0};
  if (gt == 0) out[0] = 0.0f;
}

// 32 contiguous bytes -> one K=128 fp8 MFMA operand fragment (8 VGPRs).
__device__ __forceinline__ v8i32 load_frag_g(const unsigned char* p) {
  int4 lo = *(const int4*)p;
  int4 hi = *(const int4*)(p + 16);
  return (v8i32){lo.x, lo.y, lo.z, lo.w, hi.x, hi.y, hi.z, hi.w};
}

// Per-tile epilogue: exp, diag mask, partner capture, register row-sum
// accumulation, shallow col reduce + PLAIN col-partial stores (no atomics).
__device__ __forceinline__ void tile_epilogue(
    const f32x4 acc[4][4], float rs[4][4], int rb, int cbt, int jj, int wm,
    int wn, int c, int quad, float* __restrict__ Spart,
    float* __restrict__ pos) {
  const bool isdiag = (jj == 0);
  float cs[4] = {0.f, 0.f, 0.f, 0.f};
#pragma unroll
  for (int fm = 0; fm < 4; ++fm) {
#pragma unroll
    for (int r = 0; r < 4; ++r) {
      const int grow = rb * 128 + wm * 64 + fm * 16 + quad * 4 + r;
#pragma unroll
      for (int fn = 0; fn < 4; ++fn) {
        const int gcol = cbt * 128 + wn * 64 + fn * 16 + c;
        const float logit = acc[fm][fn][r] * 10.0f;
        float e = __expf(logit);
        if (isdiag && gcol == grow) e = 0.f;     // exclude self-similarity
        if ((gcol ^ grow) == BATCH) {            // partner pair i <-> i^B
          pos[grow] = logit;                     // unique writer per element
          pos[gcol] = logit;                     // sim symmetric
        }
        rs[fm][r] += e;                          // row partial -> registers
        cs[fn] += e;                             // col partial
      }
    }
  }
  if (!isdiag) {
    // col sums: 2-deep quad shuffle, then plain store into this tile's slot.
#pragma unroll
    for (int fn = 0; fn < 4; ++fn) {
      cs[fn] += __shfl_xor(cs[fn], 16);
      cs[fn] += __shfl_xor(cs[fn], 32);
    }
    if (quad == 0) {
      float* slab = Spart + (size_t)(8 + (jj - 1) * 2 + wm) * N_TOT;
#pragma unroll
      for (int fn = 0; fn < 4; ++fn)
        slab[cbt * 128 + wn * 64 + fn * 16 + c] = cs[fn];
    }
  }
}

__global__ __launch_bounds__(256, 2) void simclr_tile_kernel(
    const unsigned char* __restrict__ zn8, float* __restrict__ Spart,
    float* __restrict__ pos) {
  const int g = blockIdx.x;                    // j-group 0..7
  const int rb = blockIdx.y;                   // row band 0..63 (A, fixed)
  const int tid = threadIdx.x;
  const int wave = tid >> 6, lane = tid & 63;
  const int wm = wave >> 1, wn = wave & 1;     // wave quadrant (2x2)
  const int c = lane & 15, quad = lane >> 4;   // MFMA lane coords

  // Row-reduction scratch; +36 pad keeps writes 2-way (free), reads clean.
  __shared__ float rowbins[128][36];

  const bool extra = (rb < 32) && (g == (rb & 7));   // j=32 tile, spread
  const int ntile = 4 + (extra ? 1 : 0);

  // A-fragments straight from global into registers, once per block.
  v8i32 af[4][2];
#pragma unroll
  for (int f = 0; f < 4; ++f) {
    const unsigned char* arow =
        zn8 + (size_t)(rb * 128 + wm * 64 + f * 16 + c) * DIM + quad * 32;
#pragma unroll
    for (int h = 0; h < 2; ++h) af[f][h] = load_frag_g(arow + h * 128);
  }

  float rs[4][4] = {{0.f, 0.f, 0.f, 0.f}, {0.f, 0.f, 0.f, 0.f},
                    {0.f, 0.f, 0.f, 0.f}, {0.f, 0.f, 0.f, 0.f}};

  f32x4 acc[4][4];
  int cbPrev = 0, jjPrev = 0;
  bool havePrev = false;

  for (int t = 0; t < ntile; ++t) {
    const int jj = (t == 4) ? 32 : (g * 4 + t);
    const int cbt = (rb + jj) & 63;

    // 1. Issue this tile's B-fragment loads (fire early).
    v8i32 bf[4][2];
#pragma unroll
    for (int f = 0; f < 4; ++f) {
      const unsigned char* brow =
          zn8 + (size_t)(cbt * 128 + wn * 64 + f * 16 + c) * DIM + quad * 32;
#pragma unroll
      for (int h = 0; h < 2; ++h) bf[f][h] = load_frag_g(brow + h * 128);
    }

    // 2. Previous tile's epilogue runs while those loads are in flight.
    if (havePrev)
      tile_epilogue(acc, rs, rb, cbPrev, jjPrev, wm, wn, c, quad, Spart, pos);

    // 3. MFMA. h=0 starts from C=0 (no acc zero-init needed).
#pragma unroll
    for (int fm = 0; fm < 4; ++fm)
#pragma unroll
      for (int fn = 0; fn < 4; ++fn)
        acc[fm][fn] = __builtin_amdgcn_mfma_scale_f32_16x16x128_f8f6f4(
            af[fm][0], bf[fn][0], (f32x4){0.f, 0.f, 0.f, 0.f},
            0, 0, 0, 0x7f, 0, 0x7f);
#pragma unroll
    for (int fm = 0; fm < 4; ++fm)
#pragma unroll
      for (int fn = 0; fn < 4; ++fn)
        acc[fm][fn] = __builtin_amdgcn_mfma_scale_f32_16x16x128_f8f6f4(
            af[fm][1], bf[fn][1], acc[fm][fn],
            0, 0, 0, 0x7f, 0, 0x7f);

    cbPrev = cbt;
    jjPrev = jj;
    havePrev = true;
  }
  tile_epilogue(acc, rs, rb, cbPrev, jjPrev, wm, wn, c, quad, Spart, pos);

  // Block-end row flush: registers -> padded LDS -> plain store (slot g).
#pragma unroll
  for (int fm = 0; fm < 4; ++fm)
#pragma unroll
    for (int r = 0; r < 4; ++r)
      rowbins[wm * 64 + fm * 16 + quad * 4 + r][wn * 16 + c] = rs[fm][r];
  __syncthreads();
  if (tid < 128) {
    const float4* p = (const float4*)rowbins[tid];
    float s = 0.f;
#pragma unroll
    for (int k = 0; k < 8; ++k) {
      float4 v = p[k];
      s += v.x + v.y + v.z + v.w;
    }
    Spart[(size_t)g * N_TOT + rb * 128 + tid] = s;   // plain store
  }
}

// loss = mean(log(sum_slots Spart) - pos). 32 blocks x 256 threads,
// coalesced slot reads, one atomicAdd(out) per block (out zeroed upstream).
__global__ __launch_bounds__(256) void finalize_kernel(
    const float* __restrict__ Spart, const float* __restrict__ pos,
    float* __restrict__ out) {
  const int tid = threadIdx.x;
  const int row = blockIdx.x * 256 + tid;
  float acc = 0.f;
#pragma unroll
  for (int s = 0; s < NSLOT; ++s) acc += Spart[(size_t)s * N_TOT + row];
  float a = __logf(acc) - pos[row];
#pragma unroll
  for (int m = 1; m <= 32; m <<= 1) a += __shfl_xor(a, m);
  __shared__ float red[4];
  if ((tid & 63) == 0) red[tid >> 6] = a;
  __syncthreads();
  if (tid == 0)
    atomicAdd(out, (red[0] + red[1] + red[2] + red[3]) * (1.0f / N_TOT));
}

extern "C" void kernel_launch(void* const* d_in, const int* in_sizes, int n_in,
                              void* d_out, int out_size, void* d_ws,
                              size_t ws_size, hipStream_t stream) {
  const float* z = (const float*)d_in[0];
  float* out = (float*)d_out;
  char* ws = (char*)d_ws;
  float* pos = (float*)ws;                                 // N floats
  float* Spart = (float*)(ws + N_TOT * sizeof(float));     // 72*N floats
  unsigned char* zn8 =
      (unsigned char*)(ws + (1 + NSLOT) * N_TOT * sizeof(float));  // N*D fp8

  normalize_kernel<<<N_TOT / 4, 256, 0, stream>>>(z, zn8, Spart, out);
  dim3 grid(8, NT_TILES);
  simclr_tile_kernel<<<grid, 256, 0, stream>>>(zn8, Spart, pos);
  finalize_kernel<<<N_TOT / 256, 256, 0, stream>>>(Spart, pos, out);
}